// Round 6
// baseline (349.154 us; speedup 1.0000x reference)
//
#include <hip/hip_runtime.h>

typedef unsigned short ushort_t;
typedef unsigned int u32;
typedef unsigned long long u64;
typedef __attribute__((ext_vector_type(4))) float f32x4;
typedef __attribute__((ext_vector_type(16))) float f32x16;
typedef __attribute__((ext_vector_type(8))) short s16x8;

__device__ __forceinline__ ushort_t f2bf(float f) {
    u32 u = __float_as_uint(f);
    u32 r = u + 0x7fffu + ((u >> 16) & 1u);
    return (ushort_t)(r >> 16);
}
__device__ __forceinline__ void cp16(const void* g, void* l) {
    __builtin_amdgcn_global_load_lds(
        (const __attribute__((address_space(1))) u32*)g,
        (__attribute__((address_space(3))) u32*)l, 16, 0, 0);
}

// ---------------- fused prep: bf16 casts + bit-mask, one launch ----------------
__global__ __launch_bounds__(256)
void prep_all(const float* __restrict__ qf, const float* __restrict__ kf,
              const float* __restrict__ vf, const float* __restrict__ Wq,
              const float* __restrict__ Wk, const float* __restrict__ Wv,
              const float* __restrict__ Wo, const int* __restrict__ m,
              ushort_t* __restrict__ oq, ushort_t* __restrict__ ok,
              ushort_t* __restrict__ ov, ushort_t* __restrict__ oWq,
              ushort_t* __restrict__ oWk, ushort_t* __restrict__ oWv,
              ushort_t* __restrict__ oWo, u32* __restrict__ mf) {
    const int bid = blockIdx.x;
    const int tid = threadIdx.x;
    if (bid < 13312) {
        const float* s; ushort_t* o; int i;
        if (bid < 12288) {
            const int part = bid >> 12, bx = bid & 4095;
            s = part == 0 ? qf : (part == 1 ? kf : vf);
            o = part == 0 ? oq : (part == 1 ? ok : ov);
            i = (bx * 256 + tid) * 4;
        } else {
            const int r = bid - 12288;
            const int part = r >> 8, bx = r & 255;
            s = part == 0 ? Wq : (part == 1 ? Wk : (part == 2 ? Wv : Wo));
            o = part == 0 ? oWq : (part == 1 ? oWk : (part == 2 ? oWv : oWo));
            i = (bx * 256 + tid) * 4;
        }
        float4 v = *(const float4*)(s + i);
        u64 pk = (u64)f2bf(v.x) | ((u64)f2bf(v.y) << 16) |
                 ((u64)f2bf(v.z) << 32) | ((u64)f2bf(v.w) << 48);
        *(u64*)(o + i) = pk;
    } else {
        // mask -> fragment-ordered bits: u32 per (b, kt64, g32=q/32, lane)
        __shared__ u32 ms32[128 * 20];
        const int r = bid - 13312;
        const int kt = r & 31, qt = (r >> 5) & 15, b = r >> 9;
        const int* mg = m + ((size_t)(b * 2048 + qt * 128)) * 2048 + kt * 64;
#pragma unroll
        for (int rep = 0; rep < 8; rep++) {
            int linear = rep * 256 + tid;
            int row = linear >> 4, ci = linear & 15;
            int4 v = *(const int4*)(mg + (size_t)row * 2048 + ci * 4);
            u32 w = (v.x ? 1u : 0u) | (v.y ? 0x100u : 0u) |
                    (v.z ? 0x10000u : 0u) | (v.w ? 0x1000000u : 0u);
            ms32[row * 20 + ci] = w;
        }
        __syncthreads();
        const int qgl = tid >> 6, L = tid & 63, hf = L >> 5, q5 = L & 31;
        const int row = qgl * 32 + q5;
        u32 rw[16];
#pragma unroll
        for (int j = 0; j < 4; j++) {
            uint4 t = *(const uint4*)&ms32[row * 20 + j * 4];
            rw[j * 4] = t.x; rw[j * 4 + 1] = t.y; rw[j * 4 + 2] = t.z; rw[j * 4 + 3] = t.w;
        }
        u32 res = 0;
#pragma unroll
        for (int mi = 0; mi < 16; mi++)
#pragma unroll
            for (int p = 0; p < 2; p++) {
                const int widx = 8 * (mi >> 3) + 2 * ((mi >> 1) & 3) + hf;
                const int shift = 8 * (2 * (mi & 1) + p);
                res |= ((rw[widx] >> shift) & 1u) << (2 * mi + p);
            }
        mf[(((size_t)b * 32 + kt) * 64 + qt * 4 + qgl) * 64 + L] = res;
    }
}

// ---------------- fused q/k/v projection: 128x128 NT GEMM ----------------
// z=0: q scaled by 0.125*log2(e), [B,H,S,64]; z=1: k [B,H,S,64]
// z=2: vT = Wv x^T stored [512][8192], kpos-axis sigma-permuted (swap 4-blocks
//      1<->2 within each 16) so attn's PV A-frag = raw 16B global loads.
__global__ __launch_bounds__(256)
void gemm_qkv(const ushort_t* __restrict__ Aq, const ushort_t* __restrict__ Ak,
              const ushort_t* __restrict__ Av, const ushort_t* __restrict__ Wq,
              const ushort_t* __restrict__ Wk, const ushort_t* __restrict__ Wv,
              const float* __restrict__ bq, const float* __restrict__ bk,
              const float* __restrict__ bv, ushort_t* __restrict__ oq,
              ushort_t* __restrict__ ok, ushort_t* __restrict__ ov) {
    constexpr int K = 512;
    const int z = blockIdx.z;
    const ushort_t* A = z == 0 ? Aq : (z == 1 ? Ak : Wv);
    const ushort_t* Bm = z == 0 ? Wq : (z == 1 ? Wk : Av);
    const float* bias = z == 0 ? bq : (z == 1 ? bk : bv);
    ushort_t* out = z == 0 ? oq : (z == 1 ? ok : ov);
    const float scale = z == 0 ? 0.18033688f : 1.0f;  // 0.125*log2(e)
    const int bm = (z == 2) ? blockIdx.y : blockIdx.x;
    const int bn = (z == 2) ? blockIdx.x : blockIdx.y;

    __shared__ ushort_t As[128 * 32];
    __shared__ ushort_t Bs[128 * 32];
    const int tid = threadIdx.x;
    const int wave = tid >> 6, lane = tid & 63, quad = lane >> 4, l16 = lane & 15;
    const int wm = (wave >> 1) * 64, wn = (wave & 1) * 64;

    const ushort_t* Ag = A + (size_t)(bm * 128 + (tid >> 2)) * K + (tid & 3) * 8;
    const ushort_t* Bg = Bm + (size_t)(bn * 128 + (tid >> 2)) * K + (tid & 3) * 8;

    f32x4 acc[4][4];
#pragma unroll
    for (int i = 0; i < 4; i++)
#pragma unroll
        for (int j = 0; j < 4; j++) acc[i][j] = (f32x4){0.f, 0.f, 0.f, 0.f};

    for (int kt = 0; kt < K; kt += 32) {
        __syncthreads();
        cp16(Ag + kt, (char*)As + tid * 16);
        cp16(Ag + 64 * K + kt, (char*)As + 4096 + tid * 16);
        cp16(Bg + kt, (char*)Bs + tid * 16);
        cp16(Bg + 64 * K + kt, (char*)Bs + 4096 + tid * 16);
        __syncthreads();
        s16x8 af[4], bf[4];
#pragma unroll
        for (int i = 0; i < 4; i++)
            af[i] = *(const s16x8*)&As[(wm + i * 16 + l16) * 32 + quad * 8];
#pragma unroll
        for (int j = 0; j < 4; j++)
            bf[j] = *(const s16x8*)&Bs[(wn + j * 16 + l16) * 32 + quad * 8];
#pragma unroll
        for (int i = 0; i < 4; i++)
#pragma unroll
            for (int j = 0; j < 4; j++)
                acc[i][j] = __builtin_amdgcn_mfma_f32_16x16x32_bf16(af[i], bf[j], acc[i][j], 0, 0, 0);
    }

    if (z == 2) {
        // sigma permutation on the kpos (column) axis within each 16-group
        const int blk = (l16 >> 2) & 3;
        const int l16p = (blk == 1 || blk == 2) ? (l16 ^ 12) : l16;
#pragma unroll
        for (int i = 0; i < 4; i++) {
            const int gm0 = bm * 128 + wm + i * 16 + quad * 4;
            const float4 b4 = *(const float4*)&bias[gm0];
#pragma unroll
            for (int j = 0; j < 4; j++) {
                const int gn = bn * 128 + wn + j * 16 + l16p;
                out[(size_t)(gm0 + 0) * 8192 + gn] = f2bf(acc[i][j][0] + b4.x);
                out[(size_t)(gm0 + 1) * 8192 + gn] = f2bf(acc[i][j][1] + b4.y);
                out[(size_t)(gm0 + 2) * 8192 + gn] = f2bf(acc[i][j][2] + b4.z);
                out[(size_t)(gm0 + 3) * 8192 + gn] = f2bf(acc[i][j][3] + b4.w);
            }
        }
    } else {
#pragma unroll
        for (int j = 0; j < 4; j++) {
            const int gn = bn * 128 + wn + j * 16 + l16;
            const float bb = bias[gn];
            const int hh = gn >> 6, dd = gn & 63;
#pragma unroll
            for (int i = 0; i < 4; i++) {
                const int gm0 = bm * 128 + wm + i * 16 + quad * 4;
                const int bi = gm0 >> 11, s0 = gm0 & 2047;
#pragma unroll
                for (int p = 0; p < 4; p++)
                    out[(((size_t)(bi * 8 + hh)) * 2048 + s0 + p) * 64 + dd] =
                        f2bf((acc[i][j][p] + bb) * scale);
            }
        }
    }
}

// ---------------- fused attention: K LDS pipeline, V prefetched to registers ----
// 1-D grid 1024, XCD-swizzled. Ks 3-deep counted-vmcnt pipeline. V is loaded
// into REGISTERS at iteration start (T14 issue-early): the ~600cyc QK+softmax
// phase covers the L2-hit latency; PV consumes the regs with the compiler's
// own waitcnt. Mask is folded into the QK accumulator init (masked = -1024.0,
// exp2 -> exact 0), removing the zero-init movs and post-exp ANDs.
// Per-iter VMEM queue: [V(t)x8][m(t+1)][K(t+2)x2] -> vmcnt(2) at next top
// drains all but the K pair.
__global__ __launch_bounds__(256, 4)
void attn(const ushort_t* __restrict__ q, const ushort_t* __restrict__ k,
          const ushort_t* __restrict__ vT, const u32* __restrict__ mf,
          ushort_t* __restrict__ po, float* __restrict__ pl) {
    __shared__ ushort_t Ks[3][64 * 64];  // 3-deep, XOR chunk-swizzled

    const int tid = threadIdx.x;
    const int bid = blockIdx.x;
    // XCD-aware decode: xcd = bid&7 (round-robin dispatch); group g in 0..63
    // appears 16x on one XCD, qt = the 16 q-tiles sharing that group's K/V.
    const int j = bid >> 3;
    const int g = ((j >> 4) << 3) | (bid & 7);
    const int qt = j & 15;
    const int hh = g & 7;
    const int zz = g >> 3;
    const int b = zz >> 1, ks = zz & 1;

    const int w = tid >> 6, L = tid & 63, hf = L >> 5, q5 = L & 31;
    const size_t bh = (size_t)b * 8 + hh;
    const ushort_t* qg = q + (bh * 2048 + qt * 128 + w * 32) * 64;
    const ushort_t* kg = k + bh * 2048 * 64 + (size_t)ks * 65536;
    const ushort_t* vg = vT + (size_t)hh * 64 * 8192 + b * 2048 + ks * 1024;
    const ushort_t* vp0 = vg + (size_t)q5 * 8192 + hf * 8;   // rows 0..31
    const ushort_t* vp1 = vp0 + (size_t)32 * 8192;           // rows 32..63
    const u32* mg = mf + (((size_t)b * 32 + ks * 16) * 64 + qt * 4 + w) * 64 + L;

    const int lin0 = tid, lin1 = 256 + tid;
    const int sr0 = lin0 >> 3, sc0 = lin0 & 7;
    const int sr1 = lin1 >> 3, sc1 = lin1 & 7;
    const int kc0 = (sc0 ^ (sr0 & 7)) * 8, kc1 = (sc1 ^ (sr1 & 7)) * 8;

    // ---- prologue: Q frags + mask(0) regs, then K(0), K(1) stages ----
    s16x8 Qf[4];
#pragma unroll
    for (int s = 0; s < 4; s++)
        Qf[s] = *(const s16x8*)(qg + q5 * 64 + s * 16 + hf * 8);
    u32 mmc = *mg;
    __builtin_amdgcn_sched_barrier(0);
    cp16(kg + (size_t)sr0 * 64 + kc0, (char*)Ks[0] + lin0 * 16);
    cp16(kg + (size_t)sr1 * 64 + kc1, (char*)Ks[0] + lin1 * 16);
    cp16(kg + 4096 + (size_t)sr0 * 64 + kc0, (char*)Ks[1] + lin0 * 16);
    cp16(kg + 4096 + (size_t)sr1 * 64 + kc1, (char*)Ks[1] + lin1 * 16);
    __builtin_amdgcn_sched_barrier(0);

    // loop-invariant swizzled LDS offsets (ushort elements), static-indexed
    int koff[4];
#pragma unroll
    for (int s = 0; s < 4; s++) koff[s] = ((2 * s + hf) ^ (q5 & 7)) * 8;
    const int row0 = q5 * 64, row1 = (32 + q5) * 64;

    f32x16 O0, O1;
#pragma unroll
    for (int i = 0; i < 16; i++) { O0[i] = 0.f; O1[i] = 0.f; }
    float rsla = 0.f, rslb = 0.f;

#define ATTN_IT(T, WAITN)                                                        \
    {                                                                            \
        __builtin_amdgcn_sched_barrier(0);                                       \
        asm volatile("s_waitcnt vmcnt(" #WAITN ")" ::: "memory");                \
        __builtin_amdgcn_sched_barrier(0);                                       \
        __builtin_amdgcn_s_barrier();                                            \
        __builtin_amdgcn_sched_barrier(0);                                       \
        s16x8 vA0[4], vA1[4];                                                    \
        _Pragma("unroll")                                                        \
        for (int s = 0; s < 4; s++) {                                            \
            vA0[s] = *(const s16x8*)(vp0 + (size_t)(T) * 64 + s * 16);           \
            vA1[s] = *(const s16x8*)(vp1 + (size_t)(T) * 64 + s * 16);           \
        }                                                                        \
        __builtin_amdgcn_sched_barrier(0);                                       \
        const u32 mm = mmc;                                                      \
        if ((T) + 1 < 16) mmc = mg[(size_t)((T) + 1) * 4096];                    \
        __builtin_amdgcn_sched_barrier(0);                                       \
        if ((T) + 2 < 16) {                                                      \
            const ushort_t* kn = kg + (size_t)((T) + 2) * 4096;                  \
            cp16(kn + (size_t)sr0 * 64 + kc0, (char*)Ks[((T) + 2) % 3] + lin0 * 16); \
            cp16(kn + (size_t)sr1 * 64 + kc1, (char*)Ks[((T) + 2) % 3] + lin1 * 16); \
        }                                                                        \
        __builtin_amdgcn_sched_barrier(0);                                       \
        const u32 nmm = ~mm;                                                     \
        f32x16 c0, c1;                                                           \
        _Pragma("unroll")                                                        \
        for (int mi = 0; mi < 16; mi++) {                                        \
            const int reg = ((mi >> 1) & 3) * 4 + (mi & 1) * 2;                  \
            const u32 i0 = ((u32)__builtin_amdgcn_sbfe((int)nmm, 2 * mi, 1)) & 0xc4800000u; \
            const u32 i1 = ((u32)__builtin_amdgcn_sbfe((int)nmm, 2 * mi + 1, 1)) & 0xc4800000u; \
            if (mi < 8) { c0[reg] = __uint_as_float(i0); c0[reg + 1] = __uint_as_float(i1); } \
            else        { c1[reg] = __uint_as_float(i0); c1[reg + 1] = __uint_as_float(i1); } \
        }                                                                        \
        _Pragma("unroll")                                                        \
        for (int s = 0; s < 4; s++) {                                            \
            const s16x8 kf0 = *(const s16x8*)&Ks[(T) % 3][row0 + koff[s]];       \
            c0 = __builtin_amdgcn_mfma_f32_32x32x16_bf16(kf0, Qf[s], c0, 0, 0, 0); \
        }                                                                        \
        _Pragma("unroll")                                                        \
        for (int s = 0; s < 4; s++) {                                            \
            const s16x8 kf1 = *(const s16x8*)&Ks[(T) % 3][row1 + koff[s]];       \
            c1 = __builtin_amdgcn_mfma_f32_32x32x16_bf16(kf1, Qf[s], c1, 0, 0, 0); \
        }                                                                        \
        u32 P[16];                                                               \
        _Pragma("unroll")                                                        \
        for (int mi = 0; mi < 16; mi++) {                                        \
            const int reg = ((mi >> 1) & 3) * 4 + (mi & 1) * 2;                  \
            const float s0 = (mi < 8) ? c0[reg] : c1[reg];                       \
            const float s1 = (mi < 8) ? c0[reg + 1] : c1[reg + 1];               \
            const float e0 = __builtin_amdgcn_exp2f(s0);                         \
            const float e1 = __builtin_amdgcn_exp2f(s1);                         \
            rsla += e0;                                                          \
            rslb += e1;                                                          \
            P[mi] = __builtin_amdgcn_perm(__float_as_uint(e1), __float_as_uint(e0), 0x07060302); \
        }                                                                        \
        _Pragma("unroll")                                                        \
        for (int s = 0; s < 4; s++) {                                            \
            union { uint4 u; s16x8 v; } pu;                                      \
            pu.u.x = P[4 * s];                                                   \
            pu.u.y = P[4 * s + 1];                                               \
            pu.u.z = P[4 * s + 2];                                               \
            pu.u.w = P[4 * s + 3];                                               \
            const s16x8 Pf = pu.v;                                               \
            O0 = __builtin_amdgcn_mfma_f32_32x32x16_bf16(vA0[s], Pf, O0, 0, 0, 0); \
            O1 = __builtin_amdgcn_mfma_f32_32x32x16_bf16(vA1[s], Pf, O1, 0, 0, 0); \
        }                                                                        \
    }

    ATTN_IT(0, 2)  ATTN_IT(1, 2)  ATTN_IT(2, 2)  ATTN_IT(3, 2)
    ATTN_IT(4, 2)  ATTN_IT(5, 2)  ATTN_IT(6, 2)  ATTN_IT(7, 2)
    ATTN_IT(8, 2)  ATTN_IT(9, 2)  ATTN_IT(10, 2) ATTN_IT(11, 2)
    ATTN_IT(12, 2) ATTN_IT(13, 2) ATTN_IT(14, 2) ATTN_IT(15, 0)
#undef ATTN_IT

    const float rsl = rsla + rslb;
    const float rst = rsl + __shfl_xor(rsl, 32);
    const int qrow = qt * 128 + w * 32 + q5;
    if (hf == 0)
        pl[(((size_t)ks * 4 + b) * 8 + hh) * 2048 + qrow] = rst;
    ushort_t* por = po + ((size_t)(ks * 4 + b) * 2048 + qrow) * 512 + hh * 64;
#pragma unroll
    for (int dh = 0; dh < 2; dh++)
#pragma unroll
        for (int r4 = 0; r4 < 4; r4++) {
            const int d = dh * 32 + r4 * 8 + hf * 4;
            const float v0 = dh ? O1[r4 * 4 + 0] : O0[r4 * 4 + 0];
            const float v1 = dh ? O1[r4 * 4 + 1] : O0[r4 * 4 + 1];
            const float v2 = dh ? O1[r4 * 4 + 2] : O0[r4 * 4 + 2];
            const float v3 = dh ? O1[r4 * 4 + 3] : O0[r4 * 4 + 3];
            u32 lo = (u32)f2bf(v0) | ((u32)f2bf(v1) << 16);
            u32 hi = (u32)f2bf(v2) | ((u32)f2bf(v3) << 16);
            *(uint2*)(por + d) = make_uint2(lo, hi);
        }
}

// ---------------- output projection with fused split-K combine ----------------
__global__ __launch_bounds__(256)
void gemm_out(const ushort_t* __restrict__ po, const float* __restrict__ pl,
              const ushort_t* __restrict__ W, const float* __restrict__ bias,
              float* __restrict__ out) {
    __shared__ ushort_t As[128 * 32];
    __shared__ ushort_t Bs[64 * 32];
    __shared__ float lls[8 * 128];
    const int tid = threadIdx.x, bm = blockIdx.x, bn = blockIdx.y;
    const int wave = tid >> 6, lane = tid & 63, quad = lane >> 4, l16 = lane & 15;

#pragma unroll
    for (int rep = 0; rep < 4; rep++) {
        const int idx = rep * 256 + tid;
        const int h = idx >> 7, r = idx & 127;
        const int gm = bm * 128 + r, b = gm >> 11, s = gm & 2047;
        const float l0 = pl[((size_t)b * 8 + h) * 2048 + s];
        const float l1 = pl[((size_t)(4 + b) * 8 + h) * 2048 + s];
        lls[idx] = 1.0f / (l0 + l1);
    }

    const ushort_t* Bg = W + (size_t)(bn * 64 + (tid >> 2)) * 512 + (tid & 3) * 8;
    const int r0 = tid >> 2, c8 = (tid & 3) * 8;

    f32x4 acc[2][4];
#pragma unroll
    for (int i = 0; i < 2; i++)
#pragma unroll
        for (int j = 0; j < 4; j++) acc[i][j] = (f32x4){0.f, 0.f, 0.f, 0.f};

    for (int kt = 0; kt < 512; kt += 32) {
        __syncthreads();
        cp16(Bg + kt, (char*)Bs + tid * 16);
        const int hidx = kt >> 6;
#pragma unroll
        for (int half = 0; half < 2; half++) {
            const int r = r0 + half * 64;
            const ushort_t* p0 = po + (size_t)(bm * 128 + r) * 512 + kt + c8;
            const ushort_t* p1 = p0 + (size_t)4 * 2048 * 512;
            const uint4 ua = *(const uint4*)p0;
            const uint4 ub = *(const uint4*)p1;
            const float inv = lls[hidx * 128 + r];
            const u32 xa[4] = {ua.x, ua.y, ua.z, ua.w};
            const u32 xb[4] = {ub.x, ub.y, ub.z, ub.w};
            u32 wo[4];
#pragma unroll
            for (int j = 0; j < 4; j++) {
                const float lo = (__uint_as_float(xa[j] << 16) +
                                  __uint_as_float(xb[j] << 16)) * inv;
                const float hi = (__uint_as_float(xa[j] & 0xffff0000u) +
                                  __uint_as_float(xb[j] & 0xffff0000u)) * inv;
                wo[j] = (u32)f2bf(lo) | ((u32)f2bf(hi) << 16);
            }
            *(uint4*)&As[r * 32 + c8] = make_uint4(wo[0], wo[1], wo[2], wo[3]);
        }
        __syncthreads();
        s16x8 af[2], bf[4];
#pragma unroll
        for (int i = 0; i < 2; i++)
            af[i] = *(const s16x8*)&As[(wave * 32 + i * 16 + l16) * 32 + quad * 8];
#pragma unroll
        for (int j = 0; j < 4; j++)
            bf[j] = *(const s16x8*)&Bs[(j * 16 + l16) * 32 + quad * 8];
#pragma unroll
        for (int i = 0; i < 2; i++)
#pragma unroll
            for (int j = 0; j < 4; j++)
                acc[i][j] = __builtin_amdgcn_mfma_f32_16x16x32_bf16(af[i], bf[j], acc[i][j], 0, 0, 0);
    }

#pragma unroll
    for (int j = 0; j < 4; j++) {
        const int gn = bn * 64 + j * 16 + l16;
        const float bb = bias[gn];
#pragma unroll
        for (int i = 0; i < 2; i++) {
            const int gm0 = bm * 128 + wave * 32 + i * 16 + quad * 4;
#pragma unroll
            for (int p = 0; p < 4; p++)
                out[(size_t)(gm0 + p) * 512 + gn] = acc[i][j][p] + bb;
        }
    }
}

// ---------------- launch ----------------
extern "C" void kernel_launch(void* const* d_in, const int* in_sizes, int n_in,
                              void* d_out, int out_size, void* d_ws, size_t ws_size,
                              hipStream_t stream) {
    const float* query = (const float*)d_in[0];
    const float* key_ = (const float*)d_in[1];
    const float* value = (const float*)d_in[2];
    const int* mask = (const int*)d_in[3];
    const float* Wq = (const float*)d_in[4];
    const float* bq = (const float*)d_in[5];
    const float* Wk = (const float*)d_in[6];
    const float* bk = (const float*)d_in[7];
    const float* Wv = (const float*)d_in[8];
    const float* bv = (const float*)d_in[9];
    const float* Wo = (const float*)d_in[10];
    const float* bo = (const float*)d_in[11];

    const size_t E = 4194304;  // 8192*512
    const size_t W = 262144;   // 512*512
    ushort_t* qb = (ushort_t*)d_ws;
    ushort_t* kb = qb + E;
    ushort_t* vb = kb + E;
    ushort_t* Wqb = vb + E;
    ushort_t* Wkb = Wqb + W;
    ushort_t* Wvb = Wkb + W;
    ushort_t* Wob = Wvb + W;
    u32* mbits = (u32*)(Wob + W);              // 2 MB
    ushort_t* qp = (ushort_t*)(mbits + (size_t)4 * 32 * 64 * 64);
    ushort_t* kp = qp + E;
    ushort_t* vTp = kp + E;   // [512][8192], sigma-permuted kpos
    ushort_t* po = vTp + E;   // bf16 partials, 2*4*2048*512
    float* pl = (float*)(po + (size_t)2 * 4 * 2048 * 512);

    prep_all<<<dim3(15360), 256, 0, stream>>>(query, key_, value, Wq, Wk, Wv, Wo,
                                              mask, qb, kb, vb, Wqb, Wkb, Wvb, Wob,
                                              mbits);

    gemm_qkv<<<dim3(64, 4, 3), 256, 0, stream>>>(qb, kb, vb, Wqb, Wkb, Wvb,
                                                 bq, bk, bv, qp, kp, vTp);

    attn<<<dim3(1024), 256, 0, stream>>>(qp, kp, vTp, mbits, po, pl);

    gemm_out<<<dim3(64, 8), 256, 0, stream>>>(po, pl, Wob, bo, (float*)d_out);
}

// Round 7
// 254.781 us; speedup vs baseline: 1.3704x; 1.3704x over previous
//
#include <hip/hip_runtime.h>

typedef unsigned short ushort_t;
typedef unsigned int u32;
typedef unsigned long long u64;
typedef __attribute__((ext_vector_type(4))) float f32x4;
typedef __attribute__((ext_vector_type(16))) float f32x16;
typedef __attribute__((ext_vector_type(8))) short s16x8;

__device__ __forceinline__ ushort_t f2bf(float f) {
    u32 u = __float_as_uint(f);
    u32 r = u + 0x7fffu + ((u >> 16) & 1u);
    return (ushort_t)(r >> 16);
}
__device__ __forceinline__ void cp16(const void* g, void* l) {
    __builtin_amdgcn_global_load_lds(
        (const __attribute__((address_space(1))) u32*)g,
        (__attribute__((address_space(3))) u32*)l, 16, 0, 0);
}

// ---------------- fused prep: bf16 casts + bit-mask, one launch ----------------
__global__ __launch_bounds__(256)
void prep_all(const float* __restrict__ qf, const float* __restrict__ kf,
              const float* __restrict__ vf, const float* __restrict__ Wq,
              const float* __restrict__ Wk, const float* __restrict__ Wv,
              const float* __restrict__ Wo, const int* __restrict__ m,
              ushort_t* __restrict__ oq, ushort_t* __restrict__ ok,
              ushort_t* __restrict__ ov, ushort_t* __restrict__ oWq,
              ushort_t* __restrict__ oWk, ushort_t* __restrict__ oWv,
              ushort_t* __restrict__ oWo, u32* __restrict__ mf) {
    const int bid = blockIdx.x;
    const int tid = threadIdx.x;
    if (bid < 13312) {
        const float* s; ushort_t* o; int i;
        if (bid < 12288) {
            const int part = bid >> 12, bx = bid & 4095;
            s = part == 0 ? qf : (part == 1 ? kf : vf);
            o = part == 0 ? oq : (part == 1 ? ok : ov);
            i = (bx * 256 + tid) * 4;
        } else {
            const int r = bid - 12288;
            const int part = r >> 8, bx = r & 255;
            s = part == 0 ? Wq : (part == 1 ? Wk : (part == 2 ? Wv : Wo));
            o = part == 0 ? oWq : (part == 1 ? oWk : (part == 2 ? oWv : oWo));
            i = (bx * 256 + tid) * 4;
        }
        float4 v = *(const float4*)(s + i);
        u64 pk = (u64)f2bf(v.x) | ((u64)f2bf(v.y) << 16) |
                 ((u64)f2bf(v.z) << 32) | ((u64)f2bf(v.w) << 48);
        *(u64*)(o + i) = pk;
    } else {
        // mask -> fragment-ordered bits: u32 per (b, kt64, g32=q/32, lane)
        __shared__ u32 ms32[128 * 20];
        const int r = bid - 13312;
        const int kt = r & 31, qt = (r >> 5) & 15, b = r >> 9;
        const int* mg = m + ((size_t)(b * 2048 + qt * 128)) * 2048 + kt * 64;
#pragma unroll
        for (int rep = 0; rep < 8; rep++) {
            int linear = rep * 256 + tid;
            int row = linear >> 4, ci = linear & 15;
            int4 v = *(const int4*)(mg + (size_t)row * 2048 + ci * 4);
            u32 w = (v.x ? 1u : 0u) | (v.y ? 0x100u : 0u) |
                    (v.z ? 0x10000u : 0u) | (v.w ? 0x1000000u : 0u);
            ms32[row * 20 + ci] = w;
        }
        __syncthreads();
        const int qgl = tid >> 6, L = tid & 63, hf = L >> 5, q5 = L & 31;
        const int row = qgl * 32 + q5;
        u32 rw[16];
#pragma unroll
        for (int j = 0; j < 4; j++) {
            uint4 t = *(const uint4*)&ms32[row * 20 + j * 4];
            rw[j * 4] = t.x; rw[j * 4 + 1] = t.y; rw[j * 4 + 2] = t.z; rw[j * 4 + 3] = t.w;
        }
        u32 res = 0;
#pragma unroll
        for (int mi = 0; mi < 16; mi++)
#pragma unroll
            for (int p = 0; p < 2; p++) {
                const int widx = 8 * (mi >> 3) + 2 * ((mi >> 1) & 3) + hf;
                const int shift = 8 * (2 * (mi & 1) + p);
                res |= ((rw[widx] >> shift) & 1u) << (2 * mi + p);
            }
        mf[(((size_t)b * 32 + kt) * 64 + qt * 4 + qgl) * 64 + L] = res;
    }
}

// ---------------- fused q/k/v projection: 128x128 NT GEMM ----------------
// z=0: q scaled by 0.125*log2(e), [B,H,S,64]; z=1: k [B,H,S,64]
// z=2: vT = Wv x^T stored [512][8192], kpos-axis sigma-permuted (swap 4-blocks
//      1<->2 within each 16) so attn's PV B-frag = raw C regs (no shuffle).
__global__ __launch_bounds__(256)
void gemm_qkv(const ushort_t* __restrict__ Aq, const ushort_t* __restrict__ Ak,
              const ushort_t* __restrict__ Av, const ushort_t* __restrict__ Wq,
              const ushort_t* __restrict__ Wk, const ushort_t* __restrict__ Wv,
              const float* __restrict__ bq, const float* __restrict__ bk,
              const float* __restrict__ bv, ushort_t* __restrict__ oq,
              ushort_t* __restrict__ ok, ushort_t* __restrict__ ov) {
    constexpr int K = 512;
    const int z = blockIdx.z;
    const ushort_t* A = z == 0 ? Aq : (z == 1 ? Ak : Wv);
    const ushort_t* Bm = z == 0 ? Wq : (z == 1 ? Wk : Av);
    const float* bias = z == 0 ? bq : (z == 1 ? bk : bv);
    ushort_t* out = z == 0 ? oq : (z == 1 ? ok : ov);
    const float scale = z == 0 ? 0.18033688f : 1.0f;  // 0.125*log2(e)
    const int bm = (z == 2) ? blockIdx.y : blockIdx.x;
    const int bn = (z == 2) ? blockIdx.x : blockIdx.y;

    __shared__ ushort_t As[128 * 32];
    __shared__ ushort_t Bs[128 * 32];
    const int tid = threadIdx.x;
    const int wave = tid >> 6, lane = tid & 63, quad = lane >> 4, l16 = lane & 15;
    const int wm = (wave >> 1) * 64, wn = (wave & 1) * 64;

    const ushort_t* Ag = A + (size_t)(bm * 128 + (tid >> 2)) * K + (tid & 3) * 8;
    const ushort_t* Bg = Bm + (size_t)(bn * 128 + (tid >> 2)) * K + (tid & 3) * 8;

    f32x4 acc[4][4];
#pragma unroll
    for (int i = 0; i < 4; i++)
#pragma unroll
        for (int j = 0; j < 4; j++) acc[i][j] = (f32x4){0.f, 0.f, 0.f, 0.f};

    for (int kt = 0; kt < K; kt += 32) {
        __syncthreads();
        cp16(Ag + kt, (char*)As + tid * 16);
        cp16(Ag + 64 * K + kt, (char*)As + 4096 + tid * 16);
        cp16(Bg + kt, (char*)Bs + tid * 16);
        cp16(Bg + 64 * K + kt, (char*)Bs + 4096 + tid * 16);
        __syncthreads();
        s16x8 af[4], bf[4];
#pragma unroll
        for (int i = 0; i < 4; i++)
            af[i] = *(const s16x8*)&As[(wm + i * 16 + l16) * 32 + quad * 8];
#pragma unroll
        for (int j = 0; j < 4; j++)
            bf[j] = *(const s16x8*)&Bs[(wn + j * 16 + l16) * 32 + quad * 8];
#pragma unroll
        for (int i = 0; i < 4; i++)
#pragma unroll
            for (int j = 0; j < 4; j++)
                acc[i][j] = __builtin_amdgcn_mfma_f32_16x16x32_bf16(af[i], bf[j], acc[i][j], 0, 0, 0);
    }

    if (z == 2) {
        // sigma permutation on the kpos (column) axis within each 16-group
        const int blk = (l16 >> 2) & 3;
        const int l16p = (blk == 1 || blk == 2) ? (l16 ^ 12) : l16;
#pragma unroll
        for (int i = 0; i < 4; i++) {
            const int gm0 = bm * 128 + wm + i * 16 + quad * 4;
            const float4 b4 = *(const float4*)&bias[gm0];
#pragma unroll
            for (int j = 0; j < 4; j++) {
                const int gn = bn * 128 + wn + j * 16 + l16p;
                out[(size_t)(gm0 + 0) * 8192 + gn] = f2bf(acc[i][j][0] + b4.x);
                out[(size_t)(gm0 + 1) * 8192 + gn] = f2bf(acc[i][j][1] + b4.y);
                out[(size_t)(gm0 + 2) * 8192 + gn] = f2bf(acc[i][j][2] + b4.z);
                out[(size_t)(gm0 + 3) * 8192 + gn] = f2bf(acc[i][j][3] + b4.w);
            }
        }
    } else {
#pragma unroll
        for (int j = 0; j < 4; j++) {
            const int gn = bn * 128 + wn + j * 16 + l16;
            const float bb = bias[gn];
            const int hh = gn >> 6, dd = gn & 63;
#pragma unroll
            for (int i = 0; i < 4; i++) {
                const int gm0 = bm * 128 + wm + i * 16 + quad * 4;
                const int bi = gm0 >> 11, s0 = gm0 & 2047;
#pragma unroll
                for (int p = 0; p < 4; p++)
                    out[(((size_t)(bi * 8 + hh)) * 2048 + s0 + p) * 64 + dd] =
                        f2bf((acc[i][j][p] + bb) * scale);
            }
        }
    }
}

// ---------------- fused attention: counted-vmcnt software pipeline (R4) ----------
// 1-D grid 1024, XCD-swizzled. Pipeline: Ks 3-deep, Vs 2-deep, mask 1-ahead.
// Per iter: wait vmcnt(2) (keeps next-next K pair in flight), raw s_barrier,
// then issue prefetches (after barrier = no WAR race on recycled buffer).
// VMEM issue order is PINNED with sched_barrier(0) between groups so the
// hardware queue is exactly [mask][V,V][K,K] per iteration -> vmcnt(2)
// provably leaves only the K(t+2) pair in flight.
__global__ __launch_bounds__(256, 4)
void attn(const ushort_t* __restrict__ q, const ushort_t* __restrict__ k,
          const ushort_t* __restrict__ vT, const u32* __restrict__ mf,
          ushort_t* __restrict__ po, float* __restrict__ pl) {
    __shared__ ushort_t Ks[3][64 * 64];  // 3-deep, XOR chunk-swizzled
    __shared__ ushort_t Vs[2][64 * 64];  // 2-deep

    const int tid = threadIdx.x;
    const int bid = blockIdx.x;
    // XCD-aware decode: xcd = bid&7 (round-robin dispatch); group g in 0..63
    // appears 16x on one XCD, qt = the 16 q-tiles sharing that group's K/V.
    const int j = bid >> 3;
    const int g = ((j >> 4) << 3) | (bid & 7);
    const int qt = j & 15;
    const int hh = g & 7;
    const int zz = g >> 3;
    const int b = zz >> 1, ks = zz & 1;

    const int w = tid >> 6, L = tid & 63, hf = L >> 5, q5 = L & 31;
    const size_t bh = (size_t)b * 8 + hh;
    const ushort_t* qg = q + (bh * 2048 + qt * 128 + w * 32) * 64;
    const ushort_t* kg = k + bh * 2048 * 64 + (size_t)ks * 65536;
    const ushort_t* vg = vT + (size_t)hh * 64 * 8192 + b * 2048 + ks * 1024;
    const u32* mg = mf + (((size_t)b * 32 + ks * 16) * 64 + qt * 4 + w) * 64 + L;

    const int lin0 = tid, lin1 = 256 + tid;
    const int sr0 = lin0 >> 3, sc0 = lin0 & 7;
    const int sr1 = lin1 >> 3, sc1 = lin1 & 7;
    const int kc0 = (sc0 ^ (sr0 & 7)) * 8, kc1 = (sc1 ^ (sr1 & 7)) * 8;

    // ---- prologue: pinned queue order [Qf x4, mask, V0 x2, K0 x2, K1 x2] ----
    s16x8 Qf[4];
#pragma unroll
    for (int s = 0; s < 4; s++)
        Qf[s] = *(const s16x8*)(qg + q5 * 64 + s * 16 + hf * 8);
    u32 mmc = *mg;
    __builtin_amdgcn_sched_barrier(0);
    cp16(vg + (size_t)sr0 * 8192 + kc0, (char*)Vs[0] + lin0 * 16);
    cp16(vg + (size_t)sr1 * 8192 + kc1, (char*)Vs[0] + lin1 * 16);
    __builtin_amdgcn_sched_barrier(0);
    cp16(kg + (size_t)sr0 * 64 + kc0, (char*)Ks[0] + lin0 * 16);
    cp16(kg + (size_t)sr1 * 64 + kc1, (char*)Ks[0] + lin1 * 16);
    cp16(kg + 4096 + (size_t)sr0 * 64 + kc0, (char*)Ks[1] + lin0 * 16);
    cp16(kg + 4096 + (size_t)sr1 * 64 + kc1, (char*)Ks[1] + lin1 * 16);
    __builtin_amdgcn_sched_barrier(0);

    // loop-invariant swizzled LDS offsets (ushort elements), static-indexed
    int koff[4];
#pragma unroll
    for (int s = 0; s < 4; s++) koff[s] = ((2 * s + hf) ^ (q5 & 7)) * 8;
    const int row0 = q5 * 64, row1 = (32 + q5) * 64;

    f32x16 O0, O1;
#pragma unroll
    for (int i = 0; i < 16; i++) { O0[i] = 0.f; O1[i] = 0.f; }
    float rsla = 0.f, rslb = 0.f;

#define ATTN_IT(T, WAITN)                                                        \
    {                                                                            \
        __builtin_amdgcn_sched_barrier(0);                                       \
        asm volatile("s_waitcnt vmcnt(" #WAITN ")" ::: "memory");                \
        __builtin_amdgcn_sched_barrier(0);                                       \
        __builtin_amdgcn_s_barrier();                                            \
        __builtin_amdgcn_sched_barrier(0);                                       \
        const u32 mm = mmc;                                                      \
        if ((T) + 1 < 16) {                                                      \
            mmc = mg[(size_t)((T) + 1) * 4096];                                  \
            __builtin_amdgcn_sched_barrier(0);                                   \
            const ushort_t* vn = vg + (size_t)((T) + 1) * 64;                    \
            cp16(vn + (size_t)sr0 * 8192 + kc0, (char*)Vs[((T) + 1) & 1] + lin0 * 16); \
            cp16(vn + (size_t)sr1 * 8192 + kc1, (char*)Vs[((T) + 1) & 1] + lin1 * 16); \
            __builtin_amdgcn_sched_barrier(0);                                   \
        }                                                                        \
        if ((T) + 2 < 16) {                                                      \
            const ushort_t* kn = kg + (size_t)((T) + 2) * 4096;                  \
            cp16(kn + (size_t)sr0 * 64 + kc0, (char*)Ks[((T) + 2) % 3] + lin0 * 16); \
            cp16(kn + (size_t)sr1 * 64 + kc1, (char*)Ks[((T) + 2) % 3] + lin1 * 16); \
            __builtin_amdgcn_sched_barrier(0);                                   \
        }                                                                        \
        f32x16 c0, c1;                                                           \
        _Pragma("unroll")                                                        \
        for (int i = 0; i < 16; i++) { c0[i] = 0.f; c1[i] = 0.f; }               \
        _Pragma("unroll")                                                        \
        for (int s = 0; s < 4; s++) {                                            \
            const s16x8 kf0 = *(const s16x8*)&Ks[(T) % 3][row0 + koff[s]];       \
            c0 = __builtin_amdgcn_mfma_f32_32x32x16_bf16(kf0, Qf[s], c0, 0, 0, 0); \
        }                                                                        \
        _Pragma("unroll")                                                        \
        for (int s = 0; s < 4; s++) {                                            \
            const s16x8 kf1 = *(const s16x8*)&Ks[(T) % 3][row1 + koff[s]];       \
            c1 = __builtin_amdgcn_mfma_f32_32x32x16_bf16(kf1, Qf[s], c1, 0, 0, 0); \
        }                                                                        \
        u32 P[16];                                                               \
        _Pragma("unroll")                                                        \
        for (int mi = 0; mi < 16; mi++) {                                        \
            const int reg = ((mi >> 1) & 3) * 4 + (mi & 1) * 2;                  \
            const u32 am0 = (u32)__builtin_amdgcn_sbfe((int)mm, 2 * mi, 1);      \
            const u32 am1 = (u32)__builtin_amdgcn_sbfe((int)mm, 2 * mi + 1, 1);  \
            const float s0 = (mi < 8) ? c0[reg] : c1[reg];                       \
            const float s1 = (mi < 8) ? c0[reg + 1] : c1[reg + 1];               \
            const u32 e0 = __float_as_uint(__builtin_amdgcn_exp2f(s0)) & am0;    \
            const u32 e1 = __float_as_uint(__builtin_amdgcn_exp2f(s1)) & am1;    \
            rsla += __uint_as_float(e0);                                         \
            rslb += __uint_as_float(e1);                                         \
            P[mi] = __builtin_amdgcn_perm(e1, e0, 0x07060302);                   \
        }                                                                        \
        _Pragma("unroll")                                                        \
        for (int s = 0; s < 4; s++) {                                            \
            union { uint4 u; s16x8 v; } pu;                                      \
            pu.u.x = P[4 * s];                                                   \
            pu.u.y = P[4 * s + 1];                                               \
            pu.u.z = P[4 * s + 2];                                               \
            pu.u.w = P[4 * s + 3];                                               \
            const s16x8 Pf = pu.v;                                               \
            const s16x8 vf0 = *(const s16x8*)&Vs[(T) & 1][row0 + koff[s]];       \
            const s16x8 vf1 = *(const s16x8*)&Vs[(T) & 1][row1 + koff[s]];       \
            O0 = __builtin_amdgcn_mfma_f32_32x32x16_bf16(vf0, Pf, O0, 0, 0, 0);  \
            O1 = __builtin_amdgcn_mfma_f32_32x32x16_bf16(vf1, Pf, O1, 0, 0, 0);  \
        }                                                                        \
    }

    ATTN_IT(0, 2)  ATTN_IT(1, 2)  ATTN_IT(2, 2)  ATTN_IT(3, 2)
    ATTN_IT(4, 2)  ATTN_IT(5, 2)  ATTN_IT(6, 2)  ATTN_IT(7, 2)
    ATTN_IT(8, 2)  ATTN_IT(9, 2)  ATTN_IT(10, 2) ATTN_IT(11, 2)
    ATTN_IT(12, 2) ATTN_IT(13, 2) ATTN_IT(14, 2) ATTN_IT(15, 0)
#undef ATTN_IT

    const float rsl = rsla + rslb;
    const float rst = rsl + __shfl_xor(rsl, 32);
    const int qrow = qt * 128 + w * 32 + q5;
    if (hf == 0)
        pl[(((size_t)ks * 4 + b) * 8 + hh) * 2048 + qrow] = rst;
    ushort_t* por = po + ((size_t)(ks * 4 + b) * 2048 + qrow) * 512 + hh * 64;
#pragma unroll
    for (int dh = 0; dh < 2; dh++)
#pragma unroll
        for (int r4 = 0; r4 < 4; r4++) {
            const int d = dh * 32 + r4 * 8 + hf * 4;
            const float v0 = dh ? O1[r4 * 4 + 0] : O0[r4 * 4 + 0];
            const float v1 = dh ? O1[r4 * 4 + 1] : O0[r4 * 4 + 1];
            const float v2 = dh ? O1[r4 * 4 + 2] : O0[r4 * 4 + 2];
            const float v3 = dh ? O1[r4 * 4 + 3] : O0[r4 * 4 + 3];
            u32 lo = (u32)f2bf(v0) | ((u32)f2bf(v1) << 16);
            u32 hi = (u32)f2bf(v2) | ((u32)f2bf(v3) << 16);
            *(uint2*)(por + d) = make_uint2(lo, hi);
        }
}

// ---------------- output projection: 2-deep prefetched split-K combine ----------
// po loads for step t+1 are issued at step t (register prefetch, T14) and the
// Bs weight stage is double-buffered, so the vmcnt(0) drain inside each
// __syncthreads happens a full iteration after issue -> HBM/L2 latency covered.
// Full unroll keeps the prefetch-parity register indices static (no scratch).
__global__ __launch_bounds__(256)
void gemm_out(const ushort_t* __restrict__ po, const float* __restrict__ pl,
              const ushort_t* __restrict__ W, const float* __restrict__ bias,
              float* __restrict__ out) {
    __shared__ ushort_t As[128 * 32];
    __shared__ ushort_t Bs[2][64 * 32];
    __shared__ float lls[8 * 128];
    const int tid = threadIdx.x, bm = blockIdx.x, bn = blockIdx.y;
    const int wave = tid >> 6, lane = tid & 63, quad = lane >> 4, l16 = lane & 15;

#pragma unroll
    for (int rep = 0; rep < 4; rep++) {
        const int idx = rep * 256 + tid;
        const int h = idx >> 7, r = idx & 127;
        const int gm = bm * 128 + r, b = gm >> 11, s = gm & 2047;
        const float l0 = pl[((size_t)b * 8 + h) * 2048 + s];
        const float l1 = pl[((size_t)(4 + b) * 8 + h) * 2048 + s];
        lls[idx] = 1.0f / (l0 + l1);
    }

    const ushort_t* Bg = W + (size_t)(bn * 64 + (tid >> 2)) * 512 + (tid & 3) * 8;
    const int r0 = tid >> 2, c8 = (tid & 3) * 8;
    const size_t SPLIT = (size_t)4 * 2048 * 512;
    const ushort_t* pb0 = po + (size_t)(bm * 128 + r0) * 512 + c8;       // half 0
    const ushort_t* pb1 = po + (size_t)(bm * 128 + r0 + 64) * 512 + c8;  // half 1

    f32x4 acc[2][4];
#pragma unroll
    for (int i = 0; i < 2; i++)
#pragma unroll
        for (int j = 0; j < 4; j++) acc[i][j] = (f32x4){0.f, 0.f, 0.f, 0.f};

    // prefetch registers, [parity][half]: a = ks0 partial, b = ks1 partial
    uint4 pa[2][2], pb[2][2];

    // ---- prologue: stage t=0 (drained at first __syncthreads) ----
    cp16(Bg + 0, (char*)Bs[0] + tid * 16);
    pa[0][0] = *(const uint4*)(pb0);
    pb[0][0] = *(const uint4*)(pb0 + SPLIT);
    pa[0][1] = *(const uint4*)(pb1);
    pb[0][1] = *(const uint4*)(pb1 + SPLIT);

#pragma unroll
    for (int t = 0; t < 16; t++) {
        const int cur = t & 1;
        __syncthreads();  // Bs[cur](t) + po(t) regs arrived; As reads of t-1 done
        if (t + 1 < 16) {
            const int nxt = (t + 1) & 1;
            cp16(Bg + (t + 1) * 32, (char*)Bs[nxt] + tid * 16);
            pa[nxt][0] = *(const uint4*)(pb0 + (t + 1) * 32);
            pb[nxt][0] = *(const uint4*)(pb0 + SPLIT + (t + 1) * 32);
            pa[nxt][1] = *(const uint4*)(pb1 + (t + 1) * 32);
            pb[nxt][1] = *(const uint4*)(pb1 + SPLIT + (t + 1) * 32);
        }
        const int hidx = t >> 1;
#pragma unroll
        for (int half = 0; half < 2; half++) {
            const int r = r0 + half * 64;
            const uint4 ua = pa[cur][half];
            const uint4 ub = pb[cur][half];
            const float inv = lls[hidx * 128 + r];
            const u32 xa[4] = {ua.x, ua.y, ua.z, ua.w};
            const u32 xb[4] = {ub.x, ub.y, ub.z, ub.w};
            u32 wo[4];
#pragma unroll
            for (int jj = 0; jj < 4; jj++) {
                const float lo = (__uint_as_float(xa[jj] << 16) +
                                  __uint_as_float(xb[jj] << 16)) * inv;
                const float hi = (__uint_as_float(xa[jj] & 0xffff0000u) +
                                  __uint_as_float(xb[jj] & 0xffff0000u)) * inv;
                wo[jj] = (u32)f2bf(lo) | ((u32)f2bf(hi) << 16);
            }
            *(uint4*)&As[r * 32 + c8] = make_uint4(wo[0], wo[1], wo[2], wo[3]);
        }
        __syncthreads();
        s16x8 af[2], bf[4];
#pragma unroll
        for (int i = 0; i < 2; i++)
            af[i] = *(const s16x8*)&As[(wave * 32 + i * 16 + l16) * 32 + quad * 8];
#pragma unroll
        for (int jj = 0; jj < 4; jj++)
            bf[jj] = *(const s16x8*)&Bs[cur][(jj * 16 + l16) * 32 + quad * 8];
#pragma unroll
        for (int i = 0; i < 2; i++)
#pragma unroll
            for (int jj = 0; jj < 4; jj++)
                acc[i][jj] = __builtin_amdgcn_mfma_f32_16x16x32_bf16(af[i], bf[jj], acc[i][jj], 0, 0, 0);
    }

#pragma unroll
    for (int jj = 0; jj < 4; jj++) {
        const int gn = bn * 64 + jj * 16 + l16;
        const float bb = bias[gn];
#pragma unroll
        for (int i = 0; i < 2; i++) {
            const int gm0 = bm * 128 + wave * 32 + i * 16 + quad * 4;
#pragma unroll
            for (int p = 0; p < 4; p++)
                out[(size_t)(gm0 + p) * 512 + gn] = acc[i][jj][p] + bb;
        }
    }
}

// ---------------- launch ----------------
extern "C" void kernel_launch(void* const* d_in, const int* in_sizes, int n_in,
                              void* d_out, int out_size, void* d_ws, size_t ws_size,
                              hipStream_t stream) {
    const float* query = (const float*)d_in[0];
    const float* key_ = (const float*)d_in[1];
    const float* value = (const float*)d_in[2];
    const int* mask = (const int*)d_in[3];
    const float* Wq = (const float*)d_in[4];
    const float* bq = (const float*)d_in[5];
    const float* Wk = (const float*)d_in[6];
    const float* bk = (const float*)d_in[7];
    const float* Wv = (const float*)d_in[8];
    const float* bv = (const float*)d_in[9];
    const float* Wo = (const float*)d_in[10];
    const float* bo = (const float*)d_in[11];

    const size_t E = 4194304;  // 8192*512
    const size_t W = 262144;   // 512*512
    ushort_t* qb = (ushort_t*)d_ws;
    ushort_t* kb = qb + E;
    ushort_t* vb = kb + E;
    ushort_t* Wqb = vb + E;
    ushort_t* Wkb = Wqb + W;
    ushort_t* Wvb = Wkb + W;
    ushort_t* Wob = Wvb + W;
    u32* mbits = (u32*)(Wob + W);              // 2 MB
    ushort_t* qp = (ushort_t*)(mbits + (size_t)4 * 32 * 64 * 64);
    ushort_t* kp = qp + E;
    ushort_t* vTp = kp + E;   // [512][8192], sigma-permuted kpos
    ushort_t* po = vTp + E;   // bf16 partials, 2*4*2048*512
    float* pl = (float*)(po + (size_t)2 * 4 * 2048 * 512);

    prep_all<<<dim3(15360), 256, 0, stream>>>(query, key_, value, Wq, Wk, Wv, Wo,
                                              mask, qb, kb, vb, Wqb, Wkb, Wvb, Wob,
                                              mbits);

    gemm_qkv<<<dim3(64, 4, 3), 256, 0, stream>>>(qb, kb, vb, Wqb, Wkb, Wvb,
                                                 bq, bk, bv, qp, kp, vTp);

    attn<<<dim3(1024), 256, 0, stream>>>(qp, kp, vTp, mbits, po, pl);

    gemm_out<<<dim3(64, 8), 256, 0, stream>>>(po, pl, Wob, bo, (float*)d_out);
}

// Round 8
// 251.362 us; speedup vs baseline: 1.3890x; 1.0136x over previous
//
#include <hip/hip_runtime.h>

typedef unsigned short ushort_t;
typedef unsigned int u32;
typedef unsigned long long u64;
typedef __attribute__((ext_vector_type(4))) float f32x4;
typedef __attribute__((ext_vector_type(16))) float f32x16;
typedef __attribute__((ext_vector_type(8))) short s16x8;

__device__ __forceinline__ ushort_t f2bf(float f) {
    u32 u = __float_as_uint(f);
    u32 r = u + 0x7fffu + ((u >> 16) & 1u);
    return (ushort_t)(r >> 16);
}
__device__ __forceinline__ void cp16(const void* g, void* l) {
    __builtin_amdgcn_global_load_lds(
        (const __attribute__((address_space(1))) u32*)g,
        (__attribute__((address_space(3))) u32*)l, 16, 0, 0);
}

// ---------------- fused prep: bf16 casts + bit-mask, one launch ----------------
// Grid 3712: blocks 0..2047 = mask bit-pack (32 KB read each, dispatched FIRST
// so the heavy blocks don't form a tail); blocks 2048..3711 = casts, each
// handling 8 chunks (13312 = 1664*8) with all 8 float4 loads issued before the
// pack+store phase -> 8 outstanding VMEM per thread (ILP latency hiding, G11).
__global__ __launch_bounds__(256)
void prep_all(const float* __restrict__ qf, const float* __restrict__ kf,
              const float* __restrict__ vf, const float* __restrict__ Wq,
              const float* __restrict__ Wk, const float* __restrict__ Wv,
              const float* __restrict__ Wo, const int* __restrict__ m,
              ushort_t* __restrict__ oq, ushort_t* __restrict__ ok,
              ushort_t* __restrict__ ov, ushort_t* __restrict__ oWq,
              ushort_t* __restrict__ oWk, ushort_t* __restrict__ oWv,
              ushort_t* __restrict__ oWo, u32* __restrict__ mf) {
    const int bid = blockIdx.x;
    const int tid = threadIdx.x;
    if (bid >= 2048) {
        const int cb = bid - 2048;  // 0..1663
        const float* sp[8];
        ushort_t* op[8];
        int ii[8];
        float4 v[8];
#pragma unroll
        for (int c = 0; c < 8; c++) {
            const int vb = cb + c * 1664;  // bijective over [0,13312)
            if (vb < 12288) {
                const int part = vb >> 12, bx = vb & 4095;
                sp[c] = part == 0 ? qf : (part == 1 ? kf : vf);
                op[c] = part == 0 ? oq : (part == 1 ? ok : ov);
                ii[c] = (bx * 256 + tid) * 4;
            } else {
                const int r = vb - 12288;
                const int part = r >> 8, bx = r & 255;
                sp[c] = part == 0 ? Wq : (part == 1 ? Wk : (part == 2 ? Wv : Wo));
                op[c] = part == 0 ? oWq : (part == 1 ? oWk : (part == 2 ? oWv : oWo));
                ii[c] = (bx * 256 + tid) * 4;
            }
            v[c] = *(const float4*)(sp[c] + ii[c]);
        }
#pragma unroll
        for (int c = 0; c < 8; c++) {
            u64 pk = (u64)f2bf(v[c].x) | ((u64)f2bf(v[c].y) << 16) |
                     ((u64)f2bf(v[c].z) << 32) | ((u64)f2bf(v[c].w) << 48);
            *(u64*)(op[c] + ii[c]) = pk;
        }
    } else {
        // mask -> fragment-ordered bits: u32 per (b, kt64, g32=q/32, lane)
        __shared__ u32 ms32[128 * 20];
        const int r = bid;
        const int kt = r & 31, qt = (r >> 5) & 15, b = r >> 9;
        const int* mg = m + ((size_t)(b * 2048 + qt * 128)) * 2048 + kt * 64;
#pragma unroll
        for (int rep = 0; rep < 8; rep++) {
            int linear = rep * 256 + tid;
            int row = linear >> 4, ci = linear & 15;
            int4 v = *(const int4*)(mg + (size_t)row * 2048 + ci * 4);
            u32 w = (v.x ? 1u : 0u) | (v.y ? 0x100u : 0u) |
                    (v.z ? 0x10000u : 0u) | (v.w ? 0x1000000u : 0u);
            ms32[row * 20 + ci] = w;
        }
        __syncthreads();
        const int qgl = tid >> 6, L = tid & 63, hf = L >> 5, q5 = L & 31;
        const int row = qgl * 32 + q5;
        u32 rw[16];
#pragma unroll
        for (int j = 0; j < 4; j++) {
            uint4 t = *(const uint4*)&ms32[row * 20 + j * 4];
            rw[j * 4] = t.x; rw[j * 4 + 1] = t.y; rw[j * 4 + 2] = t.z; rw[j * 4 + 3] = t.w;
        }
        u32 res = 0;
#pragma unroll
        for (int mi = 0; mi < 16; mi++)
#pragma unroll
            for (int p = 0; p < 2; p++) {
                const int widx = 8 * (mi >> 3) + 2 * ((mi >> 1) & 3) + hf;
                const int shift = 8 * (2 * (mi & 1) + p);
                res |= ((rw[widx] >> shift) & 1u) << (2 * mi + p);
            }
        mf[(((size_t)b * 32 + kt) * 64 + qt * 4 + qgl) * 64 + L] = res;
    }
}

// ---------------- fused q/k/v projection: 128x128 NT GEMM ----------------
// z=0: q scaled by 0.125*log2(e), [B,H,S,64]; z=1: k [B,H,S,64]
// z=2: vT = Wv x^T stored [512][8192], kpos-axis sigma-permuted (swap 4-blocks
//      1<->2 within each 16) so attn's PV B-frag = raw C regs (no shuffle).
__global__ __launch_bounds__(256)
void gemm_qkv(const ushort_t* __restrict__ Aq, const ushort_t* __restrict__ Ak,
              const ushort_t* __restrict__ Av, const ushort_t* __restrict__ Wq,
              const ushort_t* __restrict__ Wk, const ushort_t* __restrict__ Wv,
              const float* __restrict__ bq, const float* __restrict__ bk,
              const float* __restrict__ bv, ushort_t* __restrict__ oq,
              ushort_t* __restrict__ ok, ushort_t* __restrict__ ov) {
    constexpr int K = 512;
    const int z = blockIdx.z;
    const ushort_t* A = z == 0 ? Aq : (z == 1 ? Ak : Wv);
    const ushort_t* Bm = z == 0 ? Wq : (z == 1 ? Wk : Av);
    const float* bias = z == 0 ? bq : (z == 1 ? bk : bv);
    ushort_t* out = z == 0 ? oq : (z == 1 ? ok : ov);
    const float scale = z == 0 ? 0.18033688f : 1.0f;  // 0.125*log2(e)
    const int bm = (z == 2) ? blockIdx.y : blockIdx.x;
    const int bn = (z == 2) ? blockIdx.x : blockIdx.y;

    __shared__ ushort_t As[128 * 32];
    __shared__ ushort_t Bs[128 * 32];
    const int tid = threadIdx.x;
    const int wave = tid >> 6, lane = tid & 63, quad = lane >> 4, l16 = lane & 15;
    const int wm = (wave >> 1) * 64, wn = (wave & 1) * 64;

    const ushort_t* Ag = A + (size_t)(bm * 128 + (tid >> 2)) * K + (tid & 3) * 8;
    const ushort_t* Bg = Bm + (size_t)(bn * 128 + (tid >> 2)) * K + (tid & 3) * 8;

    f32x4 acc[4][4];
#pragma unroll
    for (int i = 0; i < 4; i++)
#pragma unroll
        for (int j = 0; j < 4; j++) acc[i][j] = (f32x4){0.f, 0.f, 0.f, 0.f};

    for (int kt = 0; kt < K; kt += 32) {
        __syncthreads();
        cp16(Ag + kt, (char*)As + tid * 16);
        cp16(Ag + 64 * K + kt, (char*)As + 4096 + tid * 16);
        cp16(Bg + kt, (char*)Bs + tid * 16);
        cp16(Bg + 64 * K + kt, (char*)Bs + 4096 + tid * 16);
        __syncthreads();
        s16x8 af[4], bf[4];
#pragma unroll
        for (int i = 0; i < 4; i++)
            af[i] = *(const s16x8*)&As[(wm + i * 16 + l16) * 32 + quad * 8];
#pragma unroll
        for (int j = 0; j < 4; j++)
            bf[j] = *(const s16x8*)&Bs[(wn + j * 16 + l16) * 32 + quad * 8];
#pragma unroll
        for (int i = 0; i < 4; i++)
#pragma unroll
            for (int j = 0; j < 4; j++)
                acc[i][j] = __builtin_amdgcn_mfma_f32_16x16x32_bf16(af[i], bf[j], acc[i][j], 0, 0, 0);
    }

    if (z == 2) {
        // sigma permutation on the kpos (column) axis within each 16-group
        const int blk = (l16 >> 2) & 3;
        const int l16p = (blk == 1 || blk == 2) ? (l16 ^ 12) : l16;
#pragma unroll
        for (int i = 0; i < 4; i++) {
            const int gm0 = bm * 128 + wm + i * 16 + quad * 4;
            const float4 b4 = *(const float4*)&bias[gm0];
#pragma unroll
            for (int j = 0; j < 4; j++) {
                const int gn = bn * 128 + wn + j * 16 + l16p;
                out[(size_t)(gm0 + 0) * 8192 + gn] = f2bf(acc[i][j][0] + b4.x);
                out[(size_t)(gm0 + 1) * 8192 + gn] = f2bf(acc[i][j][1] + b4.y);
                out[(size_t)(gm0 + 2) * 8192 + gn] = f2bf(acc[i][j][2] + b4.z);
                out[(size_t)(gm0 + 3) * 8192 + gn] = f2bf(acc[i][j][3] + b4.w);
            }
        }
    } else {
#pragma unroll
        for (int j = 0; j < 4; j++) {
            const int gn = bn * 128 + wn + j * 16 + l16;
            const float bb = bias[gn];
            const int hh = gn >> 6, dd = gn & 63;
#pragma unroll
            for (int i = 0; i < 4; i++) {
                const int gm0 = bm * 128 + wm + i * 16 + quad * 4;
                const int bi = gm0 >> 11, s0 = gm0 & 2047;
#pragma unroll
                for (int p = 0; p < 4; p++)
                    out[(((size_t)(bi * 8 + hh)) * 2048 + s0 + p) * 64 + dd] =
                        f2bf((acc[i][j][p] + bb) * scale);
            }
        }
    }
}

// ---------------- fused attention: counted-vmcnt software pipeline (R4) ----------
// 1-D grid 1024, XCD-swizzled. Pipeline: Ks 3-deep, Vs 2-deep, mask 1-ahead.
// Per iter: wait vmcnt(2) (keeps next-next K pair in flight), raw s_barrier,
// then issue prefetches (after barrier = no WAR race on recycled buffer).
// VMEM issue order is PINNED with sched_barrier(0) between groups so the
// hardware queue is exactly [mask][V,V][K,K] per iteration -> vmcnt(2)
// provably leaves only the K(t+2) pair in flight.
__global__ __launch_bounds__(256, 4)
void attn(const ushort_t* __restrict__ q, const ushort_t* __restrict__ k,
          const ushort_t* __restrict__ vT, const u32* __restrict__ mf,
          ushort_t* __restrict__ po, float* __restrict__ pl) {
    __shared__ ushort_t Ks[3][64 * 64];  // 3-deep, XOR chunk-swizzled
    __shared__ ushort_t Vs[2][64 * 64];  // 2-deep

    const int tid = threadIdx.x;
    const int bid = blockIdx.x;
    // XCD-aware decode: xcd = bid&7 (round-robin dispatch); group g in 0..63
    // appears 16x on one XCD, qt = the 16 q-tiles sharing that group's K/V.
    const int j = bid >> 3;
    const int g = ((j >> 4) << 3) | (bid & 7);
    const int qt = j & 15;
    const int hh = g & 7;
    const int zz = g >> 3;
    const int b = zz >> 1, ks = zz & 1;

    const int w = tid >> 6, L = tid & 63, hf = L >> 5, q5 = L & 31;
    const size_t bh = (size_t)b * 8 + hh;
    const ushort_t* qg = q + (bh * 2048 + qt * 128 + w * 32) * 64;
    const ushort_t* kg = k + bh * 2048 * 64 + (size_t)ks * 65536;
    const ushort_t* vg = vT + (size_t)hh * 64 * 8192 + b * 2048 + ks * 1024;
    const u32* mg = mf + (((size_t)b * 32 + ks * 16) * 64 + qt * 4 + w) * 64 + L;

    const int lin0 = tid, lin1 = 256 + tid;
    const int sr0 = lin0 >> 3, sc0 = lin0 & 7;
    const int sr1 = lin1 >> 3, sc1 = lin1 & 7;
    const int kc0 = (sc0 ^ (sr0 & 7)) * 8, kc1 = (sc1 ^ (sr1 & 7)) * 8;

    // ---- prologue: pinned queue order [Qf x4, mask, V0 x2, K0 x2, K1 x2] ----
    s16x8 Qf[4];
#pragma unroll
    for (int s = 0; s < 4; s++)
        Qf[s] = *(const s16x8*)(qg + q5 * 64 + s * 16 + hf * 8);
    u32 mmc = *mg;
    __builtin_amdgcn_sched_barrier(0);
    cp16(vg + (size_t)sr0 * 8192 + kc0, (char*)Vs[0] + lin0 * 16);
    cp16(vg + (size_t)sr1 * 8192 + kc1, (char*)Vs[0] + lin1 * 16);
    __builtin_amdgcn_sched_barrier(0);
    cp16(kg + (size_t)sr0 * 64 + kc0, (char*)Ks[0] + lin0 * 16);
    cp16(kg + (size_t)sr1 * 64 + kc1, (char*)Ks[0] + lin1 * 16);
    cp16(kg + 4096 + (size_t)sr0 * 64 + kc0, (char*)Ks[1] + lin0 * 16);
    cp16(kg + 4096 + (size_t)sr1 * 64 + kc1, (char*)Ks[1] + lin1 * 16);
    __builtin_amdgcn_sched_barrier(0);

    // loop-invariant swizzled LDS offsets (ushort elements), static-indexed
    int koff[4];
#pragma unroll
    for (int s = 0; s < 4; s++) koff[s] = ((2 * s + hf) ^ (q5 & 7)) * 8;
    const int row0 = q5 * 64, row1 = (32 + q5) * 64;

    f32x16 O0, O1;
#pragma unroll
    for (int i = 0; i < 16; i++) { O0[i] = 0.f; O1[i] = 0.f; }
    float rsla = 0.f, rslb = 0.f;

#define ATTN_IT(T, WAITN)                                                        \
    {                                                                            \
        __builtin_amdgcn_sched_barrier(0);                                       \
        asm volatile("s_waitcnt vmcnt(" #WAITN ")" ::: "memory");                \
        __builtin_amdgcn_sched_barrier(0);                                       \
        __builtin_amdgcn_s_barrier();                                            \
        __builtin_amdgcn_sched_barrier(0);                                       \
        const u32 mm = mmc;                                                      \
        if ((T) + 1 < 16) {                                                      \
            mmc = mg[(size_t)((T) + 1) * 4096];                                  \
            __builtin_amdgcn_sched_barrier(0);                                   \
            const ushort_t* vn = vg + (size_t)((T) + 1) * 64;                    \
            cp16(vn + (size_t)sr0 * 8192 + kc0, (char*)Vs[((T) + 1) & 1] + lin0 * 16); \
            cp16(vn + (size_t)sr1 * 8192 + kc1, (char*)Vs[((T) + 1) & 1] + lin1 * 16); \
            __builtin_amdgcn_sched_barrier(0);                                   \
        }                                                                        \
        if ((T) + 2 < 16) {                                                      \
            const ushort_t* kn = kg + (size_t)((T) + 2) * 4096;                  \
            cp16(kn + (size_t)sr0 * 64 + kc0, (char*)Ks[((T) + 2) % 3] + lin0 * 16); \
            cp16(kn + (size_t)sr1 * 64 + kc1, (char*)Ks[((T) + 2) % 3] + lin1 * 16); \
            __builtin_amdgcn_sched_barrier(0);                                   \
        }                                                                        \
        f32x16 c0, c1;                                                           \
        _Pragma("unroll")                                                        \
        for (int i = 0; i < 16; i++) { c0[i] = 0.f; c1[i] = 0.f; }               \
        _Pragma("unroll")                                                        \
        for (int s = 0; s < 4; s++) {                                            \
            const s16x8 kf0 = *(const s16x8*)&Ks[(T) % 3][row0 + koff[s]];       \
            c0 = __builtin_amdgcn_mfma_f32_32x32x16_bf16(kf0, Qf[s], c0, 0, 0, 0); \
        }                                                                        \
        _Pragma("unroll")                                                        \
        for (int s = 0; s < 4; s++) {                                            \
            const s16x8 kf1 = *(const s16x8*)&Ks[(T) % 3][row1 + koff[s]];       \
            c1 = __builtin_amdgcn_mfma_f32_32x32x16_bf16(kf1, Qf[s], c1, 0, 0, 0); \
        }                                                                        \
        u32 P[16];                                                               \
        _Pragma("unroll")                                                        \
        for (int mi = 0; mi < 16; mi++) {                                        \
            const int reg = ((mi >> 1) & 3) * 4 + (mi & 1) * 2;                  \
            const u32 am0 = (u32)__builtin_amdgcn_sbfe((int)mm, 2 * mi, 1);      \
            const u32 am1 = (u32)__builtin_amdgcn_sbfe((int)mm, 2 * mi + 1, 1);  \
            const float s0 = (mi < 8) ? c0[reg] : c1[reg];                       \
            const float s1 = (mi < 8) ? c0[reg + 1] : c1[reg + 1];               \
            const u32 e0 = __float_as_uint(__builtin_amdgcn_exp2f(s0)) & am0;    \
            const u32 e1 = __float_as_uint(__builtin_amdgcn_exp2f(s1)) & am1;    \
            rsla += __uint_as_float(e0);                                         \
            rslb += __uint_as_float(e1);                                         \
            P[mi] = __builtin_amdgcn_perm(e1, e0, 0x07060302);                   \
        }                                                                        \
        _Pragma("unroll")                                                        \
        for (int s = 0; s < 4; s++) {                                            \
            union { uint4 u; s16x8 v; } pu;                                      \
            pu.u.x = P[4 * s];                                                   \
            pu.u.y = P[4 * s + 1];                                               \
            pu.u.z = P[4 * s + 2];                                               \
            pu.u.w = P[4 * s + 3];                                               \
            const s16x8 Pf = pu.v;                                               \
            const s16x8 vf0 = *(const s16x8*)&Vs[(T) & 1][row0 + koff[s]];       \
            const s16x8 vf1 = *(const s16x8*)&Vs[(T) & 1][row1 + koff[s]];       \
            O0 = __builtin_amdgcn_mfma_f32_32x32x16_bf16(vf0, Pf, O0, 0, 0, 0);  \
            O1 = __builtin_amdgcn_mfma_f32_32x32x16_bf16(vf1, Pf, O1, 0, 0, 0);  \
        }                                                                        \
    }

    ATTN_IT(0, 2)  ATTN_IT(1, 2)  ATTN_IT(2, 2)  ATTN_IT(3, 2)
    ATTN_IT(4, 2)  ATTN_IT(5, 2)  ATTN_IT(6, 2)  ATTN_IT(7, 2)
    ATTN_IT(8, 2)  ATTN_IT(9, 2)  ATTN_IT(10, 2) ATTN_IT(11, 2)
    ATTN_IT(12, 2) ATTN_IT(13, 2) ATTN_IT(14, 2) ATTN_IT(15, 0)
#undef ATTN_IT

    const float rsl = rsla + rslb;
    const float rst = rsl + __shfl_xor(rsl, 32);
    const int qrow = qt * 128 + w * 32 + q5;
    if (hf == 0)
        pl[(((size_t)ks * 4 + b) * 8 + hh) * 2048 + qrow] = rst;
    ushort_t* por = po + ((size_t)(ks * 4 + b) * 2048 + qrow) * 512 + hh * 64;
#pragma unroll
    for (int dh = 0; dh < 2; dh++)
#pragma unroll
        for (int r4 = 0; r4 < 4; r4++) {
            const int d = dh * 32 + r4 * 8 + hf * 4;
            const float v0 = dh ? O1[r4 * 4 + 0] : O0[r4 * 4 + 0];
            const float v1 = dh ? O1[r4 * 4 + 1] : O0[r4 * 4 + 1];
            const float v2 = dh ? O1[r4 * 4 + 2] : O0[r4 * 4 + 2];
            const float v3 = dh ? O1[r4 * 4 + 3] : O0[r4 * 4 + 3];
            u32 lo = (u32)f2bf(v0) | ((u32)f2bf(v1) << 16);
            u32 hi = (u32)f2bf(v2) | ((u32)f2bf(v3) << 16);
            *(uint2*)(por + d) = make_uint2(lo, hi);
        }
}

// ---------------- output projection: 2-deep prefetched split-K combine ----------
// po loads for step t+1 are issued at step t (register prefetch, T14) and the
// Bs weight stage is double-buffered, so the vmcnt(0) drain inside each
// __syncthreads happens a full iteration after issue -> HBM/L2 latency covered.
// Full unroll keeps the prefetch-parity register indices static (no scratch).
__global__ __launch_bounds__(256)
void gemm_out(const ushort_t* __restrict__ po, const float* __restrict__ pl,
              const ushort_t* __restrict__ W, const float* __restrict__ bias,
              float* __restrict__ out) {
    __shared__ ushort_t As[128 * 32];
    __shared__ ushort_t Bs[2][64 * 32];
    __shared__ float lls[8 * 128];
    const int tid = threadIdx.x, bm = blockIdx.x, bn = blockIdx.y;
    const int wave = tid >> 6, lane = tid & 63, quad = lane >> 4, l16 = lane & 15;

#pragma unroll
    for (int rep = 0; rep < 4; rep++) {
        const int idx = rep * 256 + tid;
        const int h = idx >> 7, r = idx & 127;
        const int gm = bm * 128 + r, b = gm >> 11, s = gm & 2047;
        const float l0 = pl[((size_t)b * 8 + h) * 2048 + s];
        const float l1 = pl[((size_t)(4 + b) * 8 + h) * 2048 + s];
        lls[idx] = 1.0f / (l0 + l1);
    }

    const ushort_t* Bg = W + (size_t)(bn * 64 + (tid >> 2)) * 512 + (tid & 3) * 8;
    const int r0 = tid >> 2, c8 = (tid & 3) * 8;
    const size_t SPLIT = (size_t)4 * 2048 * 512;
    const ushort_t* pb0 = po + (size_t)(bm * 128 + r0) * 512 + c8;       // half 0
    const ushort_t* pb1 = po + (size_t)(bm * 128 + r0 + 64) * 512 + c8;  // half 1

    f32x4 acc[2][4];
#pragma unroll
    for (int i = 0; i < 2; i++)
#pragma unroll
        for (int j = 0; j < 4; j++) acc[i][j] = (f32x4){0.f, 0.f, 0.f, 0.f};

    // prefetch registers, [parity][half]: a = ks0 partial, b = ks1 partial
    uint4 pa[2][2], pb[2][2];

    // ---- prologue: stage t=0 (drained at first __syncthreads) ----
    cp16(Bg + 0, (char*)Bs[0] + tid * 16);
    pa[0][0] = *(const uint4*)(pb0);
    pb[0][0] = *(const uint4*)(pb0 + SPLIT);
    pa[0][1] = *(const uint4*)(pb1);
    pb[0][1] = *(const uint4*)(pb1 + SPLIT);

#pragma unroll
    for (int t = 0; t < 16; t++) {
        const int cur = t & 1;
        __syncthreads();  // Bs[cur](t) + po(t) regs arrived; As reads of t-1 done
        if (t + 1 < 16) {
            const int nxt = (t + 1) & 1;
            cp16(Bg + (t + 1) * 32, (char*)Bs[nxt] + tid * 16);
            pa[nxt][0] = *(const uint4*)(pb0 + (t + 1) * 32);
            pb[nxt][0] = *(const uint4*)(pb0 + SPLIT + (t + 1) * 32);
            pa[nxt][1] = *(const uint4*)(pb1 + (t + 1) * 32);
            pb[nxt][1] = *(const uint4*)(pb1 + SPLIT + (t + 1) * 32);
        }
        const int hidx = t >> 1;
#pragma unroll
        for (int half = 0; half < 2; half++) {
            const int r = r0 + half * 64;
            const uint4 ua = pa[cur][half];
            const uint4 ub = pb[cur][half];
            const float inv = lls[hidx * 128 + r];
            const u32 xa[4] = {ua.x, ua.y, ua.z, ua.w};
            const u32 xb[4] = {ub.x, ub.y, ub.z, ub.w};
            u32 wo[4];
#pragma unroll
            for (int jj = 0; jj < 4; jj++) {
                const float lo = (__uint_as_float(xa[jj] << 16) +
                                  __uint_as_float(xb[jj] << 16)) * inv;
                const float hi = (__uint_as_float(xa[jj] & 0xffff0000u) +
                                  __uint_as_float(xb[jj] & 0xffff0000u)) * inv;
                wo[jj] = (u32)f2bf(lo) | ((u32)f2bf(hi) << 16);
            }
            *(uint4*)&As[r * 32 + c8] = make_uint4(wo[0], wo[1], wo[2], wo[3]);
        }
        __syncthreads();
        s16x8 af[2], bf[4];
#pragma unroll
        for (int i = 0; i < 2; i++)
            af[i] = *(const s16x8*)&As[(wave * 32 + i * 16 + l16) * 32 + quad * 8];
#pragma unroll
        for (int jj = 0; jj < 4; jj++)
            bf[jj] = *(const s16x8*)&Bs[cur][(jj * 16 + l16) * 32 + quad * 8];
#pragma unroll
        for (int i = 0; i < 2; i++)
#pragma unroll
            for (int jj = 0; jj < 4; jj++)
                acc[i][jj] = __builtin_amdgcn_mfma_f32_16x16x32_bf16(af[i], bf[jj], acc[i][jj], 0, 0, 0);
    }

#pragma unroll
    for (int jj = 0; jj < 4; jj++) {
        const int gn = bn * 64 + jj * 16 + l16;
        const float bb = bias[gn];
#pragma unroll
        for (int i = 0; i < 2; i++) {
            const int gm0 = bm * 128 + wave * 32 + i * 16 + quad * 4;
#pragma unroll
            for (int p = 0; p < 4; p++)
                out[(size_t)(gm0 + p) * 512 + gn] = acc[i][jj][p] + bb;
        }
    }
}

// ---------------- launch ----------------
extern "C" void kernel_launch(void* const* d_in, const int* in_sizes, int n_in,
                              void* d_out, int out_size, void* d_ws, size_t ws_size,
                              hipStream_t stream) {
    const float* query = (const float*)d_in[0];
    const float* key_ = (const float*)d_in[1];
    const float* value = (const float*)d_in[2];
    const int* mask = (const int*)d_in[3];
    const float* Wq = (const float*)d_in[4];
    const float* bq = (const float*)d_in[5];
    const float* Wk = (const float*)d_in[6];
    const float* bk = (const float*)d_in[7];
    const float* Wv = (const float*)d_in[8];
    const float* bv = (const float*)d_in[9];
    const float* Wo = (const float*)d_in[10];
    const float* bo = (const float*)d_in[11];

    const size_t E = 4194304;  // 8192*512
    const size_t W = 262144;   // 512*512
    ushort_t* qb = (ushort_t*)d_ws;
    ushort_t* kb = qb + E;
    ushort_t* vb = kb + E;
    ushort_t* Wqb = vb + E;
    ushort_t* Wkb = Wqb + W;
    ushort_t* Wvb = Wkb + W;
    ushort_t* Wob = Wvb + W;
    u32* mbits = (u32*)(Wob + W);              // 2 MB
    ushort_t* qp = (ushort_t*)(mbits + (size_t)4 * 32 * 64 * 64);
    ushort_t* kp = qp + E;
    ushort_t* vTp = kp + E;   // [512][8192], sigma-permuted kpos
    ushort_t* po = vTp + E;   // bf16 partials, 2*4*2048*512
    float* pl = (float*)(po + (size_t)2 * 4 * 2048 * 512);

    prep_all<<<dim3(3712), 256, 0, stream>>>(query, key_, value, Wq, Wk, Wv, Wo,
                                             mask, qb, kb, vb, Wqb, Wkb, Wvb, Wob,
                                             mbits);

    gemm_qkv<<<dim3(64, 4, 3), 256, 0, stream>>>(qb, kb, vb, Wqb, Wkb, Wvb,
                                                 bq, bk, bv, qp, kp, vTp);

    attn<<<dim3(1024), 256, 0, stream>>>(qp, kp, vTp, mbits, po, pl);

    gemm_out<<<dim3(64, 8), 256, 0, stream>>>(po, pl, Wob, bo, (float*)d_out);
}